// Round 15
// baseline (159.041 us; speedup 1.0000x reference)
//
#include <hip/hip_runtime.h>
#include <math.h>

#define B_ROWS 4096
#define DIM    1024
#define NTOT   8192
#define NCLS   40
#define TILES2 32          // 8192 / 256
#define NTILE  528         // 32*33/2 upper-tri 256^2 tiles
#define NQUAR  64          // last 16 tiles x 4 MN-quarters (dispatched FIRST)
#define NFULL  512         // tiles 0..511 as full blocks
#define NMATD  512         // x8 waves = 4096 items
#define NNLL   8           // x512 threads = 4096 rows
#define NMAIN  (NQUAR + NFULL + NMATD + NNLL)   // 1096

typedef __attribute__((ext_vector_type(8))) short bf16x8;
typedef __attribute__((ext_vector_type(4))) float f32x4;

// ws layout (floats): [0]=nll_sum [1]=matdiff_sum [2]=sum_sq [3]=sxx [4]=syy
// [5]=smix(xy+yx) [6]=unused [7]=ticket ; [8..1032)=colsum[1024] ;
// [1032..9224)=sq[8192] ; byte 36896+ : bf16 total[8192*1024]
#define WS_TOT_BYTE_OFF 36896

#define MFMA16(d, x, y) d = __builtin_amdgcn_mfma_f32_16x16x32_bf16(x, y, d, 0, 0, 0)

__device__ __forceinline__ unsigned short f2bf(float f) {
  unsigned int u = __float_as_uint(f);
  u += 0x7fffu + ((u >> 16) & 1u);   // RNE
  return (unsigned short)(u >> 16);
}

__device__ __forceinline__ void async16(const void* g, void* l) {
  __builtin_amdgcn_global_load_lds(
      (const __attribute__((address_space(1))) unsigned int*)g,
      (__attribute__((address_space(3))) unsigned int*)l, 16, 0, 0);
}

__device__ __forceinline__ float wave_sum(float v) {
  v += __shfl_xor(v, 32);
  v += __shfl_xor(v, 16);
  v += __shfl_xor(v, 8);
  v += __shfl_xor(v, 4);
  v += __shfl_xor(v, 2);
  v += __shfl_xor(v, 1);
  return v;
}

// decode linear upper-tri id -> (bi, bj), bi <= bj, T=32
__device__ __forceinline__ void decode_tile(int p, int& bi_o, int& bj_o) {
  int bi = (int)((2 * TILES2 + 1 -
                  sqrtf((float)((2 * TILES2 + 1) * (2 * TILES2 + 1) - 8 * p))) * 0.5f);
  if (bi < 0) bi = 0;
  if (bi >= TILES2) bi = TILES2 - 1;
  int start = bi * (2 * TILES2 - bi + 1) / 2;
  while (p < start) { --bi; start = bi * (2 * TILES2 - bi + 1) / 2; }
  while (p >= start + (TILES2 - bi)) { start += TILES2 - bi; ++bi; }
  bi_o = bi; bj_o = bi + (p - start);
}

// ---------------- prep: 256 blocks x 512 threads (r13/r14-verified) ----------
__global__ __launch_bounds__(512) void prep_k(const float* __restrict__ dense,
                                              const float* __restrict__ sparse,
                                              float* __restrict__ W,
                                              unsigned short* __restrict__ tot) {
  float* colsum = W + 8;
  float* sq = W + 1032;
  const int t = threadIdx.x;
  const int lane = t & 63, wave = t >> 6;
  const int blk = blockIdx.x;
  __shared__ float colsum_l[1024];
  __shared__ float red[8];
  colsum_l[t * 2] = 0.f;
  colsum_l[t * 2 + 1] = 0.f;

  float c[4][4];
  #pragma unroll
  for (int j = 0; j < 4; ++j)
    #pragma unroll
    for (int x = 0; x < 4; ++x) c[j][x] = 0.f;

  float rowtot = 0.f;
  const int rbase = blk * 32 + wave * 4;   // 4 consecutive rows per wave
  for (int i = 0; i < 4; ++i) {
    const int r = rbase + i;
    const float* src = (r < B_ROWS) ? dense + (size_t)r * DIM
                                    : sparse + (size_t)(r - B_ROWS) * DIM;
    float sp = 0.f;
    #pragma unroll
    for (int j = 0; j < 4; ++j) {
      float4 v = ((const float4*)src)[lane + 64 * j];
      c[j][0] += v.x; c[j][1] += v.y; c[j][2] += v.z; c[j][3] += v.w;
      sp += v.x * v.x + v.y * v.y + v.z * v.z + v.w * v.w;
      ushort4 o;
      o.x = f2bf(v.x); o.y = f2bf(v.y); o.z = f2bf(v.z); o.w = f2bf(v.w);
      *(ushort4*)(tot + (size_t)r * DIM + (lane + 64 * j) * 4) = o;
    }
    sp = wave_sum(sp);
    if (lane == 0) { sq[r] = sp; rowtot += sp; }
  }
  if (lane == 0) red[wave] = rowtot;

  __syncthreads();
  #pragma unroll
  for (int j = 0; j < 4; ++j)
    #pragma unroll
    for (int x = 0; x < 4; ++x)
      atomicAdd(&colsum_l[4 * lane + 256 * j + x], c[j][x]);
  __syncthreads();
  // rotated atomic walk: disjoint start offsets -> low same-address contention
  #pragma unroll
  for (int x = 0; x < 2; ++x) {
    const int g = (t * 2 + x + blk * 64) & 1023;
    atomicAdd(&colsum[g], colsum_l[g]);
  }
  if (t == 0) {
    float s = 0.f;
    #pragma unroll
    for (int w = 0; w < 8; ++w) s += red[w];
    atomicAdd(&W[2], s);
  }
}

// ---------------- main: quarters (64) + fulls (512) + matdiff (512) + nll (8)

struct SmemMain {
  short A[4][8192];   // [plane][256 rows x 32 k] = 16KB; dbuf pair = 2 planes
  short B[4][8192];
  float sqA[256], sqB[256], red[8];
};

// full 256^2 tile, quadrant-phase schedule (m201-style): K-step = 64 cols =
// 2 planes; 4 phases per step, each = one C-quadrant (m-half x n-half) over
// full K=64 (16 MFMA).  Reads clustered 12/4/8/0; frag regs reused across
// phases (alo kept F1-F2, blo F1-F3, ahi/bhi to F4).  Staging: F1 issues
// next-step A planes, F2 next-step B planes; ONE vmcnt(0) at F4 (issue->drain
// spans 2-3 phases ~=1000cy cover).  Swizzle/frag algebra identical to r5/r14
// (counter-verified 0 conflicts, absmax 0 across 6 runs).
__device__ void gram_full_body(int p, const unsigned short* __restrict__ tot,
                               float* __restrict__ W, SmemMain& sm) {
  const float* sq = W + 1032;
  const float* colsum = W + 8;
  const int t = threadIdx.x;
  const int lane = t & 63, wave = t >> 6;
  const int wr = wave >> 2, wc = wave & 3;

  int bi, bj;
  decode_tile(p, bi, bj);

  const int r0 = t >> 2;
  const int sg = (t & 3) ^ ((r0 >> 1) & 3);
  const unsigned short* gA0 = tot + (size_t)(bi * 256 + r0) * DIM + sg * 8;
  const unsigned short* gA1 = gA0 + (size_t)128 * DIM;
  const unsigned short* gB0 = tot + (size_t)(bj * 256 + r0) * DIM + sg * 8;
  const unsigned short* gB1 = gB0 + (size_t)128 * DIM;
  const int ldo0 = t * 8, ldo1 = t * 8 + 4096;

  auto stageA = [&](int pl, short* sl) {   // pl = BK-32 plane index [0,32)
    const size_t ko = (size_t)pl * 32;
    async16(gA0 + ko, sl + ldo0);
    async16(gA1 + ko, sl + ldo1);
  };
  auto stageB = [&](int pl, short* sl) {
    const size_t ko = (size_t)pl * 32;
    async16(gB0 + ko, sl + ldo0);
    async16(gB1 + ko, sl + ldo1);
  };

  // prologue: stage step-0 planes (8 loads)
  stageA(0, &sm.A[0][0]); stageA(1, &sm.A[1][0]);
  stageB(0, &sm.B[0][0]); stageB(1, &sm.B[1][0]);

  if (t < 256) sm.sqA[t] = sq[bi * 256 + t];
  else         sm.sqB[t - 256] = sq[bj * 256 + (t - 256)];
  float csp = 0.f;
  #pragma unroll
  for (int j = 0; j < 16; ++j) { float v = colsum[lane + 64 * j]; csp += v * v; }
  csp = wave_sum(csp);
  double sumdots = (double)csp;
  double sum_sq = (double)W[2];
  double sumL2 = 2.0 * (double)NTOT * sum_sq - 2.0 * sumdots;
  double bwv = sumL2 / ((double)NTOT * (double)NTOT - (double)NTOT);
  const float cexp16 = (float)(4.0 / bwv) * 0.0625f;

  f32x4 acc[8][4];
  #pragma unroll
  for (int m = 0; m < 8; ++m)
    #pragma unroll
    for (int n = 0; n < 4; ++n) acc[m][n] = (f32x4)(0.f);

  const int q = lane >> 4;
  const int fr = lane & 15;
  const int rb = (q ^ ((fr >> 1) & 3)) << 4;
  const int aoff = (wr * 128 + fr) * 64 + rb;
  const int boff = (wc * 64 + fr) * 64 + rb;

  asm volatile("s_waitcnt vmcnt(0)" ::: "memory");
  __builtin_amdgcn_s_barrier();

  for (int s = 0; s < 16; ++s) {
    const int c0 = (s & 1) * 2, c1 = c0 + 1;
    const int n0 = 2 - c0, n1 = n0 + 1;
    const bool st = (s < 15);
    const char* Ac0 = (const char*)&sm.A[c0][0];
    const char* Ac1 = (const char*)&sm.A[c1][0];
    const char* Bc0 = (const char*)&sm.B[c0][0];
    const char* Bc1 = (const char*)&sm.B[c1][0];

    bf16x8 alo[4][2], ahi[4][2], blo[2][2], bhi[2][2];

    // ---- F1: quadrant (mlo, nlo); 12 reads; stage next-step A planes ----
    #pragma unroll
    for (int m = 0; m < 4; ++m) {
      alo[m][0] = *(const bf16x8*)(Ac0 + aoff + m * 1024);
      alo[m][1] = *(const bf16x8*)(Ac1 + aoff + m * 1024);
    }
    #pragma unroll
    for (int n = 0; n < 2; ++n) {
      blo[n][0] = *(const bf16x8*)(Bc0 + boff + n * 1024);
      blo[n][1] = *(const bf16x8*)(Bc1 + boff + n * 1024);
    }
    if (st) { stageA(2 * (s + 1), &sm.A[n0][0]); stageA(2 * (s + 1) + 1, &sm.A[n1][0]); }
    __builtin_amdgcn_s_barrier();
    asm volatile("s_waitcnt lgkmcnt(0)" ::: "memory");
    __builtin_amdgcn_s_setprio(1);
    #pragma unroll
    for (int m = 0; m < 4; ++m)
      #pragma unroll
      for (int n = 0; n < 2; ++n) {
        MFMA16(acc[m][n], alo[m][0], blo[n][0]);
        MFMA16(acc[m][n], alo[m][1], blo[n][1]);
      }
    __builtin_amdgcn_s_setprio(0);
    __builtin_amdgcn_s_barrier();

    // ---- F2: quadrant (mlo, nhi); 4 reads; stage next-step B planes ----
    #pragma unroll
    for (int n = 0; n < 2; ++n) {
      bhi[n][0] = *(const bf16x8*)(Bc0 + boff + (2 + n) * 1024);
      bhi[n][1] = *(const bf16x8*)(Bc1 + boff + (2 + n) * 1024);
    }
    if (st) { stageB(2 * (s + 1), &sm.B[n0][0]); stageB(2 * (s + 1) + 1, &sm.B[n1][0]); }
    __builtin_amdgcn_s_barrier();
    asm volatile("s_waitcnt lgkmcnt(0)" ::: "memory");
    __builtin_amdgcn_s_setprio(1);
    #pragma unroll
    for (int m = 0; m < 4; ++m)
      #pragma unroll
      for (int n = 0; n < 2; ++n) {
        MFMA16(acc[m][2 + n], alo[m][0], bhi[n][0]);
        MFMA16(acc[m][2 + n], alo[m][1], bhi[n][1]);
      }
    __builtin_amdgcn_s_setprio(0);
    __builtin_amdgcn_s_barrier();

    // ---- F3: quadrant (mhi, nlo); 8 reads ----
    #pragma unroll
    for (int m = 0; m < 4; ++m) {
      ahi[m][0] = *(const bf16x8*)(Ac0 + aoff + (4 + m) * 1024);
      ahi[m][1] = *(const bf16x8*)(Ac1 + aoff + (4 + m) * 1024);
    }
    __builtin_amdgcn_s_barrier();
    asm volatile("s_waitcnt lgkmcnt(0)" ::: "memory");
    __builtin_amdgcn_s_setprio(1);
    #pragma unroll
    for (int m = 0; m < 4; ++m)
      #pragma unroll
      for (int n = 0; n < 2; ++n) {
        MFMA16(acc[4 + m][n], ahi[m][0], blo[n][0]);
        MFMA16(acc[4 + m][n], ahi[m][1], blo[n][1]);
      }
    __builtin_amdgcn_s_setprio(0);
    __builtin_amdgcn_s_barrier();

    // ---- F4: quadrant (mhi, nhi); 0 reads; single drain of the 8 staged ----
    __builtin_amdgcn_s_setprio(1);
    #pragma unroll
    for (int m = 0; m < 4; ++m)
      #pragma unroll
      for (int n = 0; n < 2; ++n) {
        MFMA16(acc[4 + m][2 + n], ahi[m][0], bhi[n][0]);
        MFMA16(acc[4 + m][2 + n], ahi[m][1], bhi[n][1]);
      }
    __builtin_amdgcn_s_setprio(0);
    asm volatile("s_waitcnt vmcnt(0)" ::: "memory");
    __builtin_amdgcn_s_barrier();
  }

  float s = 0.f;
  const int crow = (lane >> 4) * 4;
  #pragma unroll
  for (int m = 0; m < 8; ++m) {
    #pragma unroll
    for (int n = 0; n < 4; ++n) {
      #pragma unroll
      for (int r = 0; r < 4; ++r) {
        int il = wr * 128 + 16 * m + crow + r;
        int jl = wc * 64 + 16 * n + fr;
        float l2 = sm.sqA[il] + sm.sqB[jl] - 2.f * acc[m][n][r];
        l2 = fmaxf(l2, 0.f);
        float k4 = __expf(-l2 * cexp16);
        float k3 = k4 * k4;
        float k2 = k3 * k3;
        float k1 = k2 * k2;
        float k0 = k1 * k1;
        s += k0 + k1 + k2 + k3 + k4;
      }
    }
  }
  s = wave_sum(s);
  if (lane == 0) sm.red[wave] = s;
  __syncthreads();
  if (t == 0) {
    float ts = 0.f;
    #pragma unroll
    for (int w = 0; w < 8; ++w) ts += sm.red[w];
    int idx; float wgt;
    if (bi == bj)      { idx = (bi < 16) ? 3 : 4; wgt = 1.f; }
    else if (bj < 16)  { idx = 3; wgt = 2.f; }
    else if (bi >= 16) { idx = 4; wgt = 2.f; }
    else               { idx = 5; wgt = 2.f; }
    atomicAdd(&W[idx], wgt * ts);
  }
}

// quarter tile: 128x128 output of tile (bi,bj), K=1024 (r12 body verbatim)
__device__ void gram_quarter_body(int p, int quad,
                                  const unsigned short* __restrict__ tot,
                                  float* __restrict__ W, SmemMain& sm) {
  const float* sq = W + 1032;
  const float* colsum = W + 8;
  const int t = threadIdx.x;
  const int lane = t & 63, wave = t >> 6;
  const int wr = wave >> 2, wc = wave & 3;

  int bi, bj;
  decode_tile(p, bi, bj);
  const int h = quad >> 1, v = quad & 1;
  const int rA = bi * 256 + h * 128;
  const int rB = bj * 256 + v * 128;

  const int r0 = t >> 2;              // 0..127
  const int sg = (t & 3) ^ ((r0 >> 1) & 3);
  const unsigned short* gA0 = tot + (size_t)(rA + r0) * DIM + sg * 8;
  const unsigned short* gB0 = tot + (size_t)(rB + r0) * DIM + sg * 8;
  const int ldo = t * 8;              // 512 x 16B = 8KB plane

  auto stage = [&](int kt, short* sa, short* sb) {
    const size_t ko = (size_t)kt * 32;
    async16(gA0 + ko, sa + ldo);
    async16(gB0 + ko, sb + ldo);
  };

  stage(0, &sm.A[0][0], &sm.B[0][0]);
  stage(1, &sm.A[1][0], &sm.B[1][0]);
  stage(2, &sm.A[2][0], &sm.B[2][0]);

  if (t < 128)      sm.sqA[t] = sq[rA + t];
  else if (t < 256) sm.sqB[t - 128] = sq[rB + (t - 128)];
  float csp = 0.f;
  #pragma unroll
  for (int j = 0; j < 16; ++j) { float v2 = colsum[lane + 64 * j]; csp += v2 * v2; }
  csp = wave_sum(csp);
  double sumdots = (double)csp;
  double sum_sq = (double)W[2];
  double sumL2 = 2.0 * (double)NTOT * sum_sq - 2.0 * sumdots;
  double bwv = sumL2 / ((double)NTOT * (double)NTOT - (double)NTOT);
  const float cexp16 = (float)(4.0 / bwv) * 0.0625f;

  f32x4 acc[4][2];
  #pragma unroll
  for (int m = 0; m < 4; ++m)
    #pragma unroll
    for (int n = 0; n < 2; ++n) acc[m][n] = (f32x4)(0.f);

  const int q = lane >> 4;
  const int fr = lane & 15;
  const int rb = (q ^ ((fr >> 1) & 3)) << 4;
  const int aoff = (wr * 64 + fr) * 64 + rb;   // + m*1024, m=0..3
  const int boff = (wc * 32 + fr) * 64 + rb;   // + n*1024, n=0..1

  asm volatile("s_waitcnt vmcnt(4)" ::: "memory");
  __builtin_amdgcn_s_barrier();

  for (int u = 0; u < 8; ++u) {
    #pragma unroll
    for (int j = 0; j < 4; ++j) {
      const int kt = u * 4 + j;
      const char* cA = (const char*)&sm.A[j][0];
      const char* cB = (const char*)&sm.B[j][0];
      short* stA = &sm.A[(j + 3) & 3][0];
      short* stB = &sm.B[(j + 3) & 3][0];

      bf16x8 a[4], b[2];
      #pragma unroll
      for (int m = 0; m < 4; ++m) a[m] = *(const bf16x8*)(cA + aoff + m * 1024);
      #pragma unroll
      for (int n = 0; n < 2; ++n) b[n] = *(const bf16x8*)(cB + boff + n * 1024);
      if (kt < 29) stage(kt + 3, stA, stB);
      __builtin_amdgcn_s_barrier();
      asm volatile("s_waitcnt lgkmcnt(0)" ::: "memory");
      __builtin_amdgcn_s_setprio(1);
      #pragma unroll
      for (int m = 0; m < 4; ++m)
        #pragma unroll
        for (int n = 0; n < 2; ++n) MFMA16(acc[m][n], a[m], b[n]);
      __builtin_amdgcn_s_setprio(0);
      if (kt < 29)       { asm volatile("s_waitcnt vmcnt(4)" ::: "memory"); }
      else if (kt == 29) { asm volatile("s_waitcnt vmcnt(2)" ::: "memory"); }
      else if (kt == 30) { asm volatile("s_waitcnt vmcnt(0)" ::: "memory"); }
      __builtin_amdgcn_s_barrier();
    }
  }

  float s = 0.f;
  const int crow = (lane >> 4) * 4;
  #pragma unroll
  for (int m = 0; m < 4; ++m) {
    #pragma unroll
    for (int n = 0; n < 2; ++n) {
      #pragma unroll
      for (int r = 0; r < 4; ++r) {
        int il = wr * 64 + 16 * m + crow + r;
        int jl = wc * 32 + 16 * n + fr;
        float l2 = sm.sqA[il] + sm.sqB[jl] - 2.f * acc[m][n][r];
        l2 = fmaxf(l2, 0.f);
        float k4 = __expf(-l2 * cexp16);
        float k3 = k4 * k4;
        float k2 = k3 * k3;
        float k1 = k2 * k2;
        float k0 = k1 * k1;
        s += k0 + k1 + k2 + k3 + k4;
      }
    }
  }
  s = wave_sum(s);
  if (lane == 0) sm.red[wave] = s;
  __syncthreads();
  if (t == 0) {
    float ts = 0.f;
    #pragma unroll
    for (int w = 0; w < 8; ++w) ts += sm.red[w];
    int idx; float wgt;
    if (bi == bj)      { idx = (bi < 16) ? 3 : 4; wgt = 1.f; }
    else if (bj < 16)  { idx = 3; wgt = 2.f; }
    else if (bi >= 16) { idx = 4; wgt = 2.f; }
    else               { idx = 5; wgt = 2.f; }
    atomicAdd(&W[idx], wgt * ts);
  }
}

__device__ void nll_body(int bid, const float* __restrict__ pred,
                         const int* __restrict__ tgt, float* __restrict__ W,
                         SmemMain& sm) {
  const int t = threadIdx.x;
  const int i = bid * 512 + t;
  float v = pred[(size_t)i * NCLS + tgt[i]];
  v = wave_sum(v);
  if ((t & 63) == 0) sm.red[t >> 6] = v;
  __syncthreads();
  if (t == 0) {
    float s = 0.f;
    #pragma unroll
    for (int w = 0; w < 8; ++w) s += sm.red[w];
    atomicAdd(&W[0], s);
  }
}

__device__ void matdiff_body(int bid, const float* __restrict__ trans,
                             float* __restrict__ W, SmemMain& sm) {
  const int t = threadIdx.x;
  const int lane = t & 63, wave = t >> 6;
  const int b = bid * 8 + wave;           // 1 item per wave, 8 waves, 512 blocks
  const float* Tb = trans + (size_t)b * 4096;
  const int fr = lane & 15;
  const int k8 = (lane >> 4) * 8;
  bf16x8 frag[4][2];
  #pragma unroll
  for (int m = 0; m < 4; ++m) {
    #pragma unroll
    for (int kk = 0; kk < 2; ++kk) {
      const float* p = Tb + (size_t)(16 * m + fr) * 64 + kk * 32 + k8;
      float4 u0 = *(const float4*)p;
      float4 u1 = *(const float4*)(p + 4);
      bf16x8 f;
      f[0] = (short)f2bf(u0.x); f[1] = (short)f2bf(u0.y);
      f[2] = (short)f2bf(u0.z); f[3] = (short)f2bf(u0.w);
      f[4] = (short)f2bf(u1.x); f[5] = (short)f2bf(u1.y);
      f[6] = (short)f2bf(u1.z); f[7] = (short)f2bf(u1.w);
      frag[m][kk] = f;
    }
  }
  f32x4 acc[4][4];
  #pragma unroll
  for (int m = 0; m < 4; ++m)
    #pragma unroll
    for (int n = 0; n < 4; ++n) acc[m][n] = (f32x4)(0.f);
  #pragma unroll
  for (int kk = 0; kk < 2; ++kk)
    #pragma unroll
    for (int m = 0; m < 4; ++m)
      #pragma unroll
      for (int n = 0; n < 4; ++n)
        acc[m][n] = __builtin_amdgcn_mfma_f32_16x16x32_bf16(frag[m][kk], frag[n][kk],
                                                            acc[m][n], 0, 0, 0);
  float s = 0.f;
  const int crow = (lane >> 4) * 4;
  #pragma unroll
  for (int m = 0; m < 4; ++m)
    #pragma unroll
    for (int n = 0; n < 4; ++n)
      #pragma unroll
      for (int r = 0; r < 4; ++r) {
        int grow = 16 * m + crow + r;
        int gcol = 16 * n + fr;
        float g = acc[m][n][r];
        float d = (grow == gcol) ? (1.f - g) : (-g);
        s += d * d;
      }
  s = wave_sum(s);
  if (lane == 0) sm.red[wave] = sqrtf(s);
  __syncthreads();
  if (t == 0) {
    float s8 = 0.f;
    #pragma unroll
    for (int w = 0; w < 8; ++w) s8 += sm.red[w];
    atomicAdd(&W[1], s8);
  }
}

__global__ __launch_bounds__(512, 2) void main_k(
    const float* __restrict__ pred, const int* __restrict__ tgt,
    const float* __restrict__ trans, const unsigned short* __restrict__ tot,
    float* __restrict__ W, float* __restrict__ out) {
  __shared__ SmemMain sm;
  const int blk = blockIdx.x;
  if (blk < NQUAR) {
    // quarters FIRST: pack into round 1, eliminating the 3rd-round tail
    gram_quarter_body(512 + (blk >> 2), blk & 3, tot, W, sm);
  } else if (blk < NQUAR + NFULL) {
    const int bfull = blk - NQUAR;   // XCD chunking bijective over 512
    gram_full_body((bfull & 7) * 64 + (bfull >> 3), tot, W, sm);
  } else if (blk < NQUAR + NFULL + NMATD) {
    matdiff_body(blk - NQUAR - NFULL, trans, W, sm);
  } else {
    nll_body(blk - NQUAR - NFULL - NMATD, pred, tgt, W, sm);
  }

  // ticket: last of all NMAIN blocks does the final combine
  if (threadIdx.x == 0) {
    __threadfence();
    unsigned int tk = atomicAdd((unsigned int*)(W + 7), 1u);
    if (tk == NMAIN - 1) {
      __threadfence();
      float nll = -*(volatile float*)(W + 0) / (float)B_ROWS;
      float mat =  *(volatile float*)(W + 1) / (float)B_ROWS;
      float sxx =  *(volatile float*)(W + 3);
      float syy =  *(volatile float*)(W + 4);
      float smx =  *(volatile float*)(W + 5);
      float mmd = (sxx + syy - smx) / ((float)B_ROWS * (float)B_ROWS);
      out[0] = 0.1f * nll + 0.001f * mat + 0.5f * mmd;
    }
  }
}

extern "C" void kernel_launch(void* const* d_in, const int* in_sizes, int n_in,
                              void* d_out, int out_size, void* d_ws, size_t ws_size,
                              hipStream_t stream) {
  const float* pred   = (const float*)d_in[0];
  const int*   tgt    = (const int*)d_in[1];
  const float* trans  = (const float*)d_in[2];
  const float* dense  = (const float*)d_in[3];
  const float* sparse = (const float*)d_in[4];
  float* W = (float*)d_ws;
  unsigned short* tot = (unsigned short*)((char*)d_ws + WS_TOT_BYTE_OFF);
  float* out = (float*)d_out;

  hipMemsetAsync(W, 0, 1032 * sizeof(float), stream);
  prep_k<<<dim3(256), dim3(512), 0, stream>>>(dense, sparse, W, tot);
  main_k<<<dim3(NMAIN), dim3(512), 0, stream>>>(pred, tgt, trans, tot, W, out);
}

// Round 16
// 156.605 us; speedup vs baseline: 1.0156x; 1.0156x over previous
//
#include <hip/hip_runtime.h>
#include <math.h>

#define B_ROWS 4096
#define DIM    1024
#define NTOT   8192
#define NCLS   40
#define TILES2 32          // 8192 / 256
#define NTILE  528         // 32*33/2 upper-tri 256^2 tiles
#define NQUAR  64          // last 16 tiles x 4 MN-quarters (dispatched FIRST)
#define NFULL  512         // tiles 0..511 as full blocks
#define NMATD  512         // x8 waves = 4096 items
#define NNLL   8           // x512 threads = 4096 rows
#define NMAIN  (NQUAR + NFULL + NMATD + NNLL)   // 1096

typedef __attribute__((ext_vector_type(8))) short bf16x8;
typedef __attribute__((ext_vector_type(4))) float f32x4;

// ws layout (floats): [0]=nll_sum [1]=matdiff_sum [2]=sum_sq [3]=sxx [4]=syy
// [5]=smix(xy+yx) [6]=unused [7]=ticket ; [8..1032)=colsum[1024] ;
// [1032..9224)=sq[8192] ; byte 36896+ : bf16 total[8192*1024]
#define WS_TOT_BYTE_OFF 36896

#define MFMA16(d, x, y) d = __builtin_amdgcn_mfma_f32_16x16x32_bf16(x, y, d, 0, 0, 0)

__device__ __forceinline__ unsigned short f2bf(float f) {
  unsigned int u = __float_as_uint(f);
  u += 0x7fffu + ((u >> 16) & 1u);   // RNE
  return (unsigned short)(u >> 16);
}

__device__ __forceinline__ void async16(const void* g, void* l) {
  __builtin_amdgcn_global_load_lds(
      (const __attribute__((address_space(1))) unsigned int*)g,
      (__attribute__((address_space(3))) unsigned int*)l, 16, 0, 0);
}

__device__ __forceinline__ float wave_sum(float v) {
  v += __shfl_xor(v, 32);
  v += __shfl_xor(v, 16);
  v += __shfl_xor(v, 8);
  v += __shfl_xor(v, 4);
  v += __shfl_xor(v, 2);
  v += __shfl_xor(v, 1);
  return v;
}

// decode linear upper-tri id -> (bi, bj), bi <= bj, T=32
__device__ __forceinline__ void decode_tile(int p, int& bi_o, int& bj_o) {
  int bi = (int)((2 * TILES2 + 1 -
                  sqrtf((float)((2 * TILES2 + 1) * (2 * TILES2 + 1) - 8 * p))) * 0.5f);
  if (bi < 0) bi = 0;
  if (bi >= TILES2) bi = TILES2 - 1;
  int start = bi * (2 * TILES2 - bi + 1) / 2;
  while (p < start) { --bi; start = bi * (2 * TILES2 - bi + 1) / 2; }
  while (p >= start + (TILES2 - bi)) { start += TILES2 - bi; ++bi; }
  bi_o = bi; bj_o = bi + (p - start);
}

// ---------------- prep: 256 blocks x 512 threads (r13/r14-verified) ----------
__global__ __launch_bounds__(512) void prep_k(const float* __restrict__ dense,
                                              const float* __restrict__ sparse,
                                              float* __restrict__ W,
                                              unsigned short* __restrict__ tot) {
  float* colsum = W + 8;
  float* sq = W + 1032;
  const int t = threadIdx.x;
  const int lane = t & 63, wave = t >> 6;
  const int blk = blockIdx.x;
  __shared__ float colsum_l[1024];
  __shared__ float red[8];
  colsum_l[t * 2] = 0.f;
  colsum_l[t * 2 + 1] = 0.f;

  float c[4][4];
  #pragma unroll
  for (int j = 0; j < 4; ++j)
    #pragma unroll
    for (int x = 0; x < 4; ++x) c[j][x] = 0.f;

  float rowtot = 0.f;
  const int rbase = blk * 32 + wave * 4;   // 4 consecutive rows per wave
  for (int i = 0; i < 4; ++i) {
    const int r = rbase + i;
    const float* src = (r < B_ROWS) ? dense + (size_t)r * DIM
                                    : sparse + (size_t)(r - B_ROWS) * DIM;
    float sp = 0.f;
    #pragma unroll
    for (int j = 0; j < 4; ++j) {
      float4 v = ((const float4*)src)[lane + 64 * j];
      c[j][0] += v.x; c[j][1] += v.y; c[j][2] += v.z; c[j][3] += v.w;
      sp += v.x * v.x + v.y * v.y + v.z * v.z + v.w * v.w;
      ushort4 o;
      o.x = f2bf(v.x); o.y = f2bf(v.y); o.z = f2bf(v.z); o.w = f2bf(v.w);
      *(ushort4*)(tot + (size_t)r * DIM + (lane + 64 * j) * 4) = o;
    }
    sp = wave_sum(sp);
    if (lane == 0) { sq[r] = sp; rowtot += sp; }
  }
  if (lane == 0) red[wave] = rowtot;

  __syncthreads();
  #pragma unroll
  for (int j = 0; j < 4; ++j)
    #pragma unroll
    for (int x = 0; x < 4; ++x)
      atomicAdd(&colsum_l[4 * lane + 256 * j + x], c[j][x]);
  __syncthreads();
  // rotated atomic walk: disjoint start offsets -> low same-address contention
  #pragma unroll
  for (int x = 0; x < 2; ++x) {
    const int g = (t * 2 + x + blk * 64) & 1023;
    atomicAdd(&colsum[g], colsum_l[g]);
  }
  if (t == 0) {
    float s = 0.f;
    #pragma unroll
    for (int w = 0; w < 8; ++w) s += red[w];
    atomicAdd(&W[2], s);
  }
}

// ---------------- main: quarters (64) + fulls (512) + matdiff (512) + nll (8)
// (r14 VERBATIM: best measured total 157.1 us, absmax 0)

struct SmemMain {
  short A[4][8192];   // [slot][256 rows x 32 k] = 16KB per slot
  short B[4][8192];
  float sqA[256], sqB[256], red[8];
};

// full 256^2 tile: r5 body VERBATIM (125-135 us kernel, reproduced 6x)
__device__ void gram_full_body(int p, const unsigned short* __restrict__ tot,
                               float* __restrict__ W, SmemMain& sm) {
  const float* sq = W + 1032;
  const float* colsum = W + 8;
  const int t = threadIdx.x;
  const int lane = t & 63, wave = t >> 6;
  const int wr = wave >> 2, wc = wave & 3;

  int bi, bj;
  decode_tile(p, bi, bj);

  const int r0 = t >> 2;
  const int sg = (t & 3) ^ ((r0 >> 1) & 3);
  const unsigned short* gA0 = tot + (size_t)(bi * 256 + r0) * DIM + sg * 8;
  const unsigned short* gA1 = gA0 + (size_t)128 * DIM;
  const unsigned short* gB0 = tot + (size_t)(bj * 256 + r0) * DIM + sg * 8;
  const unsigned short* gB1 = gB0 + (size_t)128 * DIM;
  const int ldo0 = t * 8, ldo1 = t * 8 + 4096;

  auto stageA = [&](int kt, short* sl) {
    const size_t ko = (size_t)kt * 32;
    async16(gA0 + ko, sl + ldo0);
    async16(gA1 + ko, sl + ldo1);
  };
  auto stageB = [&](int kt, short* sl) {
    const size_t ko = (size_t)kt * 32;
    async16(gB0 + ko, sl + ldo0);
    async16(gB1 + ko, sl + ldo1);
  };

  stageA(0, &sm.A[0][0]); stageB(0, &sm.B[0][0]);
  stageA(1, &sm.A[1][0]); stageB(1, &sm.B[1][0]);
  stageA(2, &sm.A[2][0]); stageB(2, &sm.B[2][0]);

  if (t < 256) sm.sqA[t] = sq[bi * 256 + t];
  else         sm.sqB[t - 256] = sq[bj * 256 + (t - 256)];
  float csp = 0.f;
  #pragma unroll
  for (int j = 0; j < 16; ++j) { float v = colsum[lane + 64 * j]; csp += v * v; }
  csp = wave_sum(csp);
  double sumdots = (double)csp;
  double sum_sq = (double)W[2];
  double sumL2 = 2.0 * (double)NTOT * sum_sq - 2.0 * sumdots;
  double bwv = sumL2 / ((double)NTOT * (double)NTOT - (double)NTOT);
  const float cexp16 = (float)(4.0 / bwv) * 0.0625f;

  f32x4 acc[8][4];
  #pragma unroll
  for (int m = 0; m < 8; ++m)
    #pragma unroll
    for (int n = 0; n < 4; ++n) acc[m][n] = (f32x4)(0.f);

  const int q = lane >> 4;
  const int fr = lane & 15;
  const int rb = (q ^ ((fr >> 1) & 3)) << 4;
  const int aoff = (wr * 128 + fr) * 64 + rb;
  const int boff = (wc * 64 + fr) * 64 + rb;

  asm volatile("s_waitcnt vmcnt(8)" ::: "memory");
  __builtin_amdgcn_s_barrier();

  for (int u = 0; u < 8; ++u) {
    #pragma unroll
    for (int j = 0; j < 4; ++j) {
      const int kt = u * 4 + j;
      const char* cA = (const char*)&sm.A[j][0];
      const char* cB = (const char*)&sm.B[j][0];
      short* stA = &sm.A[(j + 3) & 3][0];
      short* stB = &sm.B[(j + 3) & 3][0];
      const bool st = (kt < 29);

      bf16x8 a[4], b[4];

      // ---- ph0: m0-3 x n0-3 ----
      #pragma unroll
      for (int m = 0; m < 4; ++m) a[m] = *(const bf16x8*)(cA + aoff + m * 1024);
      #pragma unroll
      for (int n = 0; n < 4; ++n) b[n] = *(const bf16x8*)(cB + boff + n * 1024);
      if (st) stageA(kt + 3, stA);
      __builtin_amdgcn_s_barrier();
      asm volatile("s_waitcnt lgkmcnt(0)" ::: "memory");
      __builtin_amdgcn_s_setprio(1);
      #pragma unroll
      for (int m = 0; m < 4; ++m)
        #pragma unroll
        for (int n = 0; n < 4; ++n) MFMA16(acc[m][n], a[m], b[n]);
      __builtin_amdgcn_s_setprio(0);
      __builtin_amdgcn_s_barrier();

      // ---- ph1: m4-7 x n0-3 (b[] reused from regs) ----
      #pragma unroll
      for (int m = 0; m < 4; ++m) a[m] = *(const bf16x8*)(cA + aoff + (4 + m) * 1024);
      if (st) stageB(kt + 3, stB);
      __builtin_amdgcn_s_barrier();
      asm volatile("s_waitcnt lgkmcnt(0)" ::: "memory");
      __builtin_amdgcn_s_setprio(1);
      #pragma unroll
      for (int m = 0; m < 4; ++m)
        #pragma unroll
        for (int n = 0; n < 4; ++n) MFMA16(acc[4 + m][n], a[m], b[n]);
      __builtin_amdgcn_s_setprio(0);
      if (kt < 29)       { asm volatile("s_waitcnt vmcnt(8)" ::: "memory"); }
      else if (kt == 29) { asm volatile("s_waitcnt vmcnt(4)" ::: "memory"); }
      else if (kt == 30) { asm volatile("s_waitcnt vmcnt(0)" ::: "memory"); }
      __builtin_amdgcn_s_barrier();
    }
  }

  float s = 0.f;
  const int crow = (lane >> 4) * 4;
  #pragma unroll
  for (int m = 0; m < 8; ++m) {
    #pragma unroll
    for (int n = 0; n < 4; ++n) {
      #pragma unroll
      for (int r = 0; r < 4; ++r) {
        int il = wr * 128 + 16 * m + crow + r;
        int jl = wc * 64 + 16 * n + fr;
        float l2 = sm.sqA[il] + sm.sqB[jl] - 2.f * acc[m][n][r];
        l2 = fmaxf(l2, 0.f);
        float k4 = __expf(-l2 * cexp16);
        float k3 = k4 * k4;
        float k2 = k3 * k3;
        float k1 = k2 * k2;
        float k0 = k1 * k1;
        s += k0 + k1 + k2 + k3 + k4;
      }
    }
  }
  s = wave_sum(s);
  if (lane == 0) sm.red[wave] = s;
  __syncthreads();
  if (t == 0) {
    float ts = 0.f;
    #pragma unroll
    for (int w = 0; w < 8; ++w) ts += sm.red[w];
    int idx; float wgt;
    if (bi == bj)      { idx = (bi < 16) ? 3 : 4; wgt = 1.f; }
    else if (bj < 16)  { idx = 3; wgt = 2.f; }
    else if (bi >= 16) { idx = 4; wgt = 2.f; }
    else               { idx = 5; wgt = 2.f; }
    atomicAdd(&W[idx], wgt * ts);
  }
}

// quarter tile: 128x128 output of tile (bi,bj), K=1024 (r12 body verbatim)
__device__ void gram_quarter_body(int p, int quad,
                                  const unsigned short* __restrict__ tot,
                                  float* __restrict__ W, SmemMain& sm) {
  const float* sq = W + 1032;
  const float* colsum = W + 8;
  const int t = threadIdx.x;
  const int lane = t & 63, wave = t >> 6;
  const int wr = wave >> 2, wc = wave & 3;

  int bi, bj;
  decode_tile(p, bi, bj);
  const int h = quad >> 1, v = quad & 1;
  const int rA = bi * 256 + h * 128;
  const int rB = bj * 256 + v * 128;

  const int r0 = t >> 2;              // 0..127
  const int sg = (t & 3) ^ ((r0 >> 1) & 3);
  const unsigned short* gA0 = tot + (size_t)(rA + r0) * DIM + sg * 8;
  const unsigned short* gB0 = tot + (size_t)(rB + r0) * DIM + sg * 8;
  const int ldo = t * 8;              // 512 x 16B = 8KB plane

  auto stage = [&](int kt, short* sa, short* sb) {
    const size_t ko = (size_t)kt * 32;
    async16(gA0 + ko, sa + ldo);
    async16(gB0 + ko, sb + ldo);
  };

  stage(0, &sm.A[0][0], &sm.B[0][0]);
  stage(1, &sm.A[1][0], &sm.B[1][0]);
  stage(2, &sm.A[2][0], &sm.B[2][0]);

  if (t < 128)      sm.sqA[t] = sq[rA + t];
  else if (t < 256) sm.sqB[t - 128] = sq[rB + (t - 128)];
  float csp = 0.f;
  #pragma unroll
  for (int j = 0; j < 16; ++j) { float v2 = colsum[lane + 64 * j]; csp += v2 * v2; }
  csp = wave_sum(csp);
  double sumdots = (double)csp;
  double sum_sq = (double)W[2];
  double sumL2 = 2.0 * (double)NTOT * sum_sq - 2.0 * sumdots;
  double bwv = sumL2 / ((double)NTOT * (double)NTOT - (double)NTOT);
  const float cexp16 = (float)(4.0 / bwv) * 0.0625f;

  f32x4 acc[4][2];
  #pragma unroll
  for (int m = 0; m < 4; ++m)
    #pragma unroll
    for (int n = 0; n < 2; ++n) acc[m][n] = (f32x4)(0.f);

  const int q = lane >> 4;
  const int fr = lane & 15;
  const int rb = (q ^ ((fr >> 1) & 3)) << 4;
  const int aoff = (wr * 64 + fr) * 64 + rb;   // + m*1024, m=0..3
  const int boff = (wc * 32 + fr) * 64 + rb;   // + n*1024, n=0..1

  asm volatile("s_waitcnt vmcnt(4)" ::: "memory");
  __builtin_amdgcn_s_barrier();

  for (int u = 0; u < 8; ++u) {
    #pragma unroll
    for (int j = 0; j < 4; ++j) {
      const int kt = u * 4 + j;
      const char* cA = (const char*)&sm.A[j][0];
      const char* cB = (const char*)&sm.B[j][0];
      short* stA = &sm.A[(j + 3) & 3][0];
      short* stB = &sm.B[(j + 3) & 3][0];

      bf16x8 a[4], b[2];
      #pragma unroll
      for (int m = 0; m < 4; ++m) a[m] = *(const bf16x8*)(cA + aoff + m * 1024);
      #pragma unroll
      for (int n = 0; n < 2; ++n) b[n] = *(const bf16x8*)(cB + boff + n * 1024);
      if (kt < 29) stage(kt + 3, stA, stB);
      __builtin_amdgcn_s_barrier();
      asm volatile("s_waitcnt lgkmcnt(0)" ::: "memory");
      __builtin_amdgcn_s_setprio(1);
      #pragma unroll
      for (int m = 0; m < 4; ++m)
        #pragma unroll
        for (int n = 0; n < 2; ++n) MFMA16(acc[m][n], a[m], b[n]);
      __builtin_amdgcn_s_setprio(0);
      if (kt < 29)       { asm volatile("s_waitcnt vmcnt(4)" ::: "memory"); }
      else if (kt == 29) { asm volatile("s_waitcnt vmcnt(2)" ::: "memory"); }
      else if (kt == 30) { asm volatile("s_waitcnt vmcnt(0)" ::: "memory"); }
      __builtin_amdgcn_s_barrier();
    }
  }

  float s = 0.f;
  const int crow = (lane >> 4) * 4;
  #pragma unroll
  for (int m = 0; m < 4; ++m) {
    #pragma unroll
    for (int n = 0; n < 2; ++n) {
      #pragma unroll
      for (int r = 0; r < 4; ++r) {
        int il = wr * 64 + 16 * m + crow + r;
        int jl = wc * 32 + 16 * n + fr;
        float l2 = sm.sqA[il] + sm.sqB[jl] - 2.f * acc[m][n][r];
        l2 = fmaxf(l2, 0.f);
        float k4 = __expf(-l2 * cexp16);
        float k3 = k4 * k4;
        float k2 = k3 * k3;
        float k1 = k2 * k2;
        float k0 = k1 * k1;
        s += k0 + k1 + k2 + k3 + k4;
      }
    }
  }
  s = wave_sum(s);
  if (lane == 0) sm.red[wave] = s;
  __syncthreads();
  if (t == 0) {
    float ts = 0.f;
    #pragma unroll
    for (int w = 0; w < 8; ++w) ts += sm.red[w];
    int idx; float wgt;
    if (bi == bj)      { idx = (bi < 16) ? 3 : 4; wgt = 1.f; }
    else if (bj < 16)  { idx = 3; wgt = 2.f; }
    else if (bi >= 16) { idx = 4; wgt = 2.f; }
    else               { idx = 5; wgt = 2.f; }
    atomicAdd(&W[idx], wgt * ts);
  }
}

__device__ void nll_body(int bid, const float* __restrict__ pred,
                         const int* __restrict__ tgt, float* __restrict__ W,
                         SmemMain& sm) {
  const int t = threadIdx.x;
  const int i = bid * 512 + t;
  float v = pred[(size_t)i * NCLS + tgt[i]];
  v = wave_sum(v);
  if ((t & 63) == 0) sm.red[t >> 6] = v;
  __syncthreads();
  if (t == 0) {
    float s = 0.f;
    #pragma unroll
    for (int w = 0; w < 8; ++w) s += sm.red[w];
    atomicAdd(&W[0], s);
  }
}

__device__ void matdiff_body(int bid, const float* __restrict__ trans,
                             float* __restrict__ W, SmemMain& sm) {
  const int t = threadIdx.x;
  const int lane = t & 63, wave = t >> 6;
  const int b = bid * 8 + wave;           // 1 item per wave, 8 waves, 512 blocks
  const float* Tb = trans + (size_t)b * 4096;
  const int fr = lane & 15;
  const int k8 = (lane >> 4) * 8;
  bf16x8 frag[4][2];
  #pragma unroll
  for (int m = 0; m < 4; ++m) {
    #pragma unroll
    for (int kk = 0; kk < 2; ++kk) {
      const float* p = Tb + (size_t)(16 * m + fr) * 64 + kk * 32 + k8;
      float4 u0 = *(const float4*)p;
      float4 u1 = *(const float4*)(p + 4);
      bf16x8 f;
      f[0] = (short)f2bf(u0.x); f[1] = (short)f2bf(u0.y);
      f[2] = (short)f2bf(u0.z); f[3] = (short)f2bf(u0.w);
      f[4] = (short)f2bf(u1.x); f[5] = (short)f2bf(u1.y);
      f[6] = (short)f2bf(u1.z); f[7] = (short)f2bf(u1.w);
      frag[m][kk] = f;
    }
  }
  f32x4 acc[4][4];
  #pragma unroll
  for (int m = 0; m < 4; ++m)
    #pragma unroll
    for (int n = 0; n < 4; ++n) acc[m][n] = (f32x4)(0.f);
  #pragma unroll
  for (int kk = 0; kk < 2; ++kk)
    #pragma unroll
    for (int m = 0; m < 4; ++m)
      #pragma unroll
      for (int n = 0; n < 4; ++n)
        acc[m][n] = __builtin_amdgcn_mfma_f32_16x16x32_bf16(frag[m][kk], frag[n][kk],
                                                            acc[m][n], 0, 0, 0);
  float s = 0.f;
  const int crow = (lane >> 4) * 4;
  #pragma unroll
  for (int m = 0; m < 4; ++m)
    #pragma unroll
    for (int n = 0; n < 4; ++n)
      #pragma unroll
      for (int r = 0; r < 4; ++r) {
        int grow = 16 * m + crow + r;
        int gcol = 16 * n + fr;
        float g = acc[m][n][r];
        float d = (grow == gcol) ? (1.f - g) : (-g);
        s += d * d;
      }
  s = wave_sum(s);
  if (lane == 0) sm.red[wave] = sqrtf(s);
  __syncthreads();
  if (t == 0) {
    float s8 = 0.f;
    #pragma unroll
    for (int w = 0; w < 8; ++w) s8 += sm.red[w];
    atomicAdd(&W[1], s8);
  }
}

__global__ __launch_bounds__(512, 2) void main_k(
    const float* __restrict__ pred, const int* __restrict__ tgt,
    const float* __restrict__ trans, const unsigned short* __restrict__ tot,
    float* __restrict__ W, float* __restrict__ out) {
  __shared__ SmemMain sm;
  const int blk = blockIdx.x;
  if (blk < NQUAR) {
    // quarters FIRST: pack into round 1, eliminating the 3rd-round tail
    gram_quarter_body(512 + (blk >> 2), blk & 3, tot, W, sm);
  } else if (blk < NQUAR + NFULL) {
    const int bfull = blk - NQUAR;   // XCD chunking bijective over 512
    gram_full_body((bfull & 7) * 64 + (bfull >> 3), tot, W, sm);
  } else if (blk < NQUAR + NFULL + NMATD) {
    matdiff_body(blk - NQUAR - NFULL, trans, W, sm);
  } else {
    nll_body(blk - NQUAR - NFULL - NMATD, pred, tgt, W, sm);
  }

  // ticket: last of all NMAIN blocks does the final combine
  if (threadIdx.x == 0) {
    __threadfence();
    unsigned int tk = atomicAdd((unsigned int*)(W + 7), 1u);
    if (tk == NMAIN - 1) {
      __threadfence();
      float nll = -*(volatile float*)(W + 0) / (float)B_ROWS;
      float mat =  *(volatile float*)(W + 1) / (float)B_ROWS;
      float sxx =  *(volatile float*)(W + 3);
      float syy =  *(volatile float*)(W + 4);
      float smx =  *(volatile float*)(W + 5);
      float mmd = (sxx + syy - smx) / ((float)B_ROWS * (float)B_ROWS);
      out[0] = 0.1f * nll + 0.001f * mat + 0.5f * mmd;
    }
  }
}

extern "C" void kernel_launch(void* const* d_in, const int* in_sizes, int n_in,
                              void* d_out, int out_size, void* d_ws, size_t ws_size,
                              hipStream_t stream) {
  const float* pred   = (const float*)d_in[0];
  const int*   tgt    = (const int*)d_in[1];
  const float* trans  = (const float*)d_in[2];
  const float* dense  = (const float*)d_in[3];
  const float* sparse = (const float*)d_in[4];
  float* W = (float*)d_ws;
  unsigned short* tot = (unsigned short*)((char*)d_ws + WS_TOT_BYTE_OFF);
  float* out = (float*)d_out;

  hipMemsetAsync(W, 0, 1032 * sizeof(float), stream);
  prep_k<<<dim3(256), dim3(512), 0, stream>>>(dense, sparse, W, tot);
  main_k<<<dim3(NMAIN), dim3(512), 0, stream>>>(pred, tgt, trans, tot, W, out);
}